// Round 1
// baseline (945.251 us; speedup 1.0000x reference)
//
#include <hip/hip_runtime.h>
#include <math.h>

using u16 = unsigned short;
using bf16x8 = __attribute__((ext_vector_type(8))) short;
using f32x4  = __attribute__((ext_vector_type(4))) float;

#define DEV static __device__ __forceinline__

DEV u16 f2bf(float f) {
  union { float f; unsigned u; } v; v.f = f;
  unsigned u = v.u + 0x7fffu + ((v.u >> 16) & 1u);
  return (u16)(u >> 16);
}

DEV void gload16(const void* g, void* l) {
  __builtin_amdgcn_global_load_lds(
      (const __attribute__((address_space(1))) void*)g,
      (__attribute__((address_space(3))) void*)l, 16, 0, 0);
}

// ---------------- prep kernels ----------------
__global__ void k_conv_bf16(const float* __restrict__ in, u16* __restrict__ out, int n) {
  int i = blockIdx.x * 256 + threadIdx.x;
  if (i < n) out[i] = f2bf(in[i]);
}

// in: f32 [K][Nin] row-major ; out: bf16 [Nout][K] (n-major).
// pack==1: n' = d2*48+j maps to n = d2*47+j for j<47, j==47 -> 0 (pad).
__global__ void k_transconv(const float* __restrict__ in, u16* __restrict__ out,
                            int K, int Nin, int Nout, int pack) {
  __shared__ float t[32][33];
  int kb = blockIdx.x * 32, nb = blockIdx.y * 32;
  int tx = threadIdx.x & 31, ty = threadIdx.x >> 5;  // 32 x 8
  #pragma unroll
  for (int i = 0; i < 4; ++i) {
    int k = kb + ty + i * 8;
    int no = nb + tx;
    float v = 0.f;
    if (k < K && no < Nout) {
      if (pack) {
        int r = no % 48;
        if (r < 47) v = in[(size_t)k * Nin + (no / 48) * 47 + r];
      } else {
        v = in[(size_t)k * Nin + no];
      }
    }
    t[ty + i * 8][tx] = v;
  }
  __syncthreads();
  #pragma unroll
  for (int i = 0; i < 4; ++i) {
    int no = nb + ty + i * 8;
    int k = kb + tx;
    if (no < Nout && k < K) out[(size_t)no * K + k] = f2bf(t[tx][ty + i * 8]);
  }
}

// ---------------- GEMM + ReLU (BM=128,BN=128,BK=32, 4 waves) ----------------
__global__ __launch_bounds__(256)
void k_gemm_relu(const u16* __restrict__ A, const u16* __restrict__ Bt,
                 const float* __restrict__ bias, u16* __restrict__ C,
                 int N, int K) {
  constexpr int BM = 128, BN = 128, BK = 32;
  __shared__ __align__(16) u16 lds[(BM + BN) * BK];
  int tid = threadIdx.x, w = tid >> 6, lane = tid & 63;
  int bn = blockIdx.x, bm = blockIdx.y;
  int brow = bm * BM, bcol = bn * BN;
  int wm = w >> 1, wn = w & 1;
  int fr = lane & 15, fg = lane >> 4;
  f32x4 acc[4][4];
  #pragma unroll
  for (int i = 0; i < 4; ++i)
    #pragma unroll
    for (int j = 0; j < 4; ++j) acc[i][j] = (f32x4){0.f, 0.f, 0.f, 0.f};

  constexpr int ACH = BM * BK / 8;         // 512 chunks of 16B for A
  constexpr int CALLS = (BM + BN) * BK / 8 / 64;  // 16 wave-calls

  for (int kt = 0; kt < K; kt += BK) {
    for (int j = 0; j * 4 + w < CALLS; ++j) {
      int cb = (j * 4 + w) * 64;
      int c = cb + lane;
      const u16* g;
      if (c < ACH) {
        int row = c >> 2, c8 = c & 3;
        g = A + (size_t)(brow + row) * K + kt + c8 * 8;
      } else {
        int b = c - ACH;
        int nn = b >> 2, c8 = b & 3;
        g = Bt + (size_t)(bcol + nn) * K + kt + c8 * 8;
      }
      gload16(g, &lds[cb * 8]);
    }
    asm volatile("s_waitcnt vmcnt(0)" ::: "memory");
    __syncthreads();

    const u16* Al = lds;
    const u16* Bl = lds + BM * BK;
    bf16x8 af[4], bfr[4];
    #pragma unroll
    for (int mi = 0; mi < 4; ++mi)
      af[mi] = *(const bf16x8*)&Al[(wm * 64 + mi * 16 + fr) * BK + fg * 8];
    #pragma unroll
    for (int ni = 0; ni < 4; ++ni)
      bfr[ni] = *(const bf16x8*)&Bl[(wn * 64 + ni * 16 + fr) * BK + fg * 8];
    #pragma unroll
    for (int mi = 0; mi < 4; ++mi)
      #pragma unroll
      for (int ni = 0; ni < 4; ++ni)
        acc[mi][ni] = __builtin_amdgcn_mfma_f32_16x16x32_bf16(af[mi], bfr[ni], acc[mi][ni], 0, 0, 0);
    __syncthreads();
  }

  #pragma unroll
  for (int ni = 0; ni < 4; ++ni) {
    int col = bcol + wn * 64 + ni * 16 + fr;
    float bb = bias[col];
    #pragma unroll
    for (int mi = 0; mi < 4; ++mi) {
      #pragma unroll
      for (int q = 0; q < 4; ++q) {
        int row = brow + wm * 64 + mi * 16 + fg * 4 + q;
        float vv = acc[mi][ni][q] + bb;
        C[(size_t)row * N + col] = f2bf(vv > 0.f ? vv : 0.f);
      }
    }
  }
}

// ------- GEMM3 fused with RQS spline (BM=128, BN=96 = 2 d2-groups of 48) -------
__global__ __launch_bounds__(256)
void k_gemm_spline(const u16* __restrict__ A, const u16* __restrict__ Bt,
                   const float* __restrict__ b2, const float* __restrict__ x2,
                   float* __restrict__ y2, float* __restrict__ ldpart,
                   int K) {
  constexpr int BM = 128, BN = 96, BK = 32;
  constexpr int LDP = 100;  // padded f32 row stride for p-tile
  __shared__ __align__(16) unsigned char smem[BM * LDP * 4];  // 51200 B
  u16*   lds  = (u16*)smem;
  float* plds = (float*)smem;
  int tid = threadIdx.x, w = tid >> 6, lane = tid & 63;
  int bn = blockIdx.x, bm = blockIdx.y;
  int brow = bm * BM;
  int wm = w >> 1, wn = w & 1;
  int fr = lane & 15, fg = lane >> 4;
  f32x4 acc[4][3];
  #pragma unroll
  for (int i = 0; i < 4; ++i)
    #pragma unroll
    for (int j = 0; j < 3; ++j) acc[i][j] = (f32x4){0.f, 0.f, 0.f, 0.f};

  constexpr int ACH = BM * BK / 8;                 // 512
  constexpr int CALLS = (BM + BN) * BK / 8 / 64;   // 14

  for (int kt = 0; kt < K; kt += BK) {
    for (int j = 0; j * 4 + w < CALLS; ++j) {
      int cb = (j * 4 + w) * 64;
      int c = cb + lane;
      const u16* g;
      if (c < ACH) {
        int row = c >> 2, c8 = c & 3;
        g = A + (size_t)(brow + row) * K + kt + c8 * 8;
      } else {
        int b = c - ACH;
        int nn = b >> 2, c8 = b & 3;
        g = Bt + (size_t)(bn * BN + nn) * K + kt + c8 * 8;
      }
      gload16(g, &lds[cb * 8]);
    }
    asm volatile("s_waitcnt vmcnt(0)" ::: "memory");
    __syncthreads();

    const u16* Al = lds;
    const u16* Bl = lds + BM * BK;
    bf16x8 af[4], bfr[3];
    #pragma unroll
    for (int mi = 0; mi < 4; ++mi)
      af[mi] = *(const bf16x8*)&Al[(wm * 64 + mi * 16 + fr) * BK + fg * 8];
    #pragma unroll
    for (int ni = 0; ni < 3; ++ni)
      bfr[ni] = *(const bf16x8*)&Bl[(wn * 48 + ni * 16 + fr) * BK + fg * 8];
    #pragma unroll
    for (int mi = 0; mi < 4; ++mi)
      #pragma unroll
      for (int ni = 0; ni < 3; ++ni)
        acc[mi][ni] = __builtin_amdgcn_mfma_f32_16x16x32_bf16(af[mi], bfr[ni], acc[mi][ni], 0, 0, 0);
    __syncthreads();
  }

  // p-tile -> LDS (transpose from fragment layout to [row][col])
  #pragma unroll
  for (int mi = 0; mi < 4; ++mi)
    #pragma unroll
    for (int ni = 0; ni < 3; ++ni)
      #pragma unroll
      for (int q = 0; q < 4; ++q)
        plds[(wm * 64 + mi * 16 + fg * 4 + q) * LDP + (wn * 48 + ni * 16 + fr)] = acc[mi][ni][q];
  __syncthreads();

  // one spline eval per thread: row = tid>>1 (128 rows), g = tid&1 (2 d2-groups)
  int row = tid >> 1, g = tid & 1;
  int grow = brow + row;
  int d2 = bn * 2 + g;
  const float* pr = plds + row * LDP + g * 48;
  const float* bb = b2 + (size_t)d2 * 47;

  float wv[16], hv[16];
  #pragma unroll
  for (int j = 0; j < 16; ++j) wv[j] = pr[j] + bb[j];
  #pragma unroll
  for (int j = 0; j < 16; ++j) hv[j] = pr[16 + j] + bb[16 + j];

  float x = x2[(size_t)grow * 256 + d2];
  float xc = fminf(fmaxf(x, -3.f), 3.f);

  float mw = wv[0];
  #pragma unroll
  for (int j = 1; j < 16; ++j) mw = fmaxf(mw, wv[j]);
  float sw = 0.f;
  #pragma unroll
  for (int j = 0; j < 16; ++j) { wv[j] = __expf(wv[j] - mw); sw += wv[j]; }
  float scw = 0.984f / sw;  // (1 - 16*0.001)/sum

  float mh = hv[0];
  #pragma unroll
  for (int j = 1; j < 16; ++j) mh = fmaxf(mh, hv[j]);
  float sh = 0.f;
  #pragma unroll
  for (int j = 0; j < 16; ++j) { hv[j] = __expf(hv[j] - mh); sh += hv[j]; }
  float sch = 0.984f / sh;

  // widths[j] = 0.001 + wv[j]*scw ; cw_full[i] = 6*cumsum - 3
  int idx = 0;
  float xk = -3.f, cum = 0.f;
  #pragma unroll
  for (int i = 1; i <= 15; ++i) {
    cum += 0.001f + wv[i - 1] * scw;
    float cwi = 6.f * cum - 3.f;
    if (xc >= cwi) { idx = i; xk = cwi; }
  }
  float yk = -3.f, cumh = 0.f;
  #pragma unroll
  for (int i = 1; i <= 15; ++i) {
    cumh += 0.001f + hv[i - 1] * sch;
    float chi = 6.f * cumh - 3.f;
    if (i == idx) yk = chi;
  }
  float wk = 1.f, hk = 1.f;
  #pragma unroll
  for (int i = 0; i < 16; ++i) {
    if (i == idx) {
      wk = 6.f * (0.001f + wv[i] * scw);
      hk = 6.f * (0.001f + hv[i] * sch);
    }
  }
  float dk = 1.f, dk1 = 1.f;  // d[0] = d[16] = 1 exactly
  #pragma unroll
  for (int i = 1; i <= 15; ++i) {
    float u = pr[32 + i - 1] + bb[32 + i - 1];
    float e = __expf(u);
    float dd = 0.001f + (u > 15.f ? u : log1pf(e));
    if (i == idx) dk = dd;
    if (i == idx + 1) dk1 = dd;
  }

  float sk = hk / wk;
  float th = (xc - xk) / wk;
  float om = 1.f - th;
  float t1m = th * om;
  float den = sk + (dk + dk1 - 2.f * sk) * t1m;
  float y = yk + hk * (sk * th * th + dk * t1m) / den;
  float deriv = sk * sk * (dk1 * th * th + 2.f * sk * t1m + dk * om * om) / (den * den);
  bool inside = (x > -3.f) && (x < 3.f);
  float yout = inside ? y : x;
  float ld = inside ? __logf(deriv) : 0.f;

  y2[(size_t)grow * 256 + d2] = yout;
  float tot = ld + __shfl_xor(ld, 1, 64);
  if (g == 0) ldpart[(size_t)bn * 16384 + grow] = tot;
}

__global__ void k_reduce_ld(const float* __restrict__ part, float* __restrict__ out) {
  int r = blockIdx.x * 256 + threadIdx.x;
  float s = 0.f;
  for (int j = 0; j < 128; ++j) s += part[(size_t)j * 16384 + r];
  out[r] = s;
}

// ---------------- launch ----------------
extern "C" void kernel_launch(void* const* d_in, const int* in_sizes, int n_in,
                              void* d_out, int out_size, void* d_ws, size_t ws_size,
                              hipStream_t stream) {
  const float* x1 = (const float*)d_in[0];
  const float* x2 = (const float*)d_in[1];
  const float* W0 = (const float*)d_in[2];
  const float* b0 = (const float*)d_in[3];
  const float* W1 = (const float*)d_in[4];
  const float* b1 = (const float*)d_in[5];
  const float* W2 = (const float*)d_in[6];
  const float* b2 = (const float*)d_in[7];
  float* y2 = (float*)d_out;
  float* logdet = y2 + (size_t)16384 * 256;

  char* ws = (char*)d_ws;
  u16* W2t = (u16*)ws;                                   // 12288*1024*2 = 25165824
  u16* W0t = (u16*)(ws + 25165824);                      // 1024*256*2  =   524288
  u16* W1t = (u16*)(ws + 25165824 + 524288);             // 1024*1024*2 =  2097152
  u16* x1b = (u16*)(ws + 27787264);                      // 16384*256*2 =  8388608
  float* ldp = (float*)(ws + 27787264);                  // aliases x1b (dead by GEMM3)
  u16* h1  = (u16*)(ws + 36175872);                      // 16384*1024*2 = 33554432
  u16* h2  = (u16*)(ws + 69730304);                      // 33554432; total 103284736

  k_conv_bf16<<<16384, 256, 0, stream>>>(x1, x1b, 16384 * 256);
  k_transconv<<<dim3(8, 32), 256, 0, stream>>>(W0, W0t, 256, 1024, 1024, 0);
  k_transconv<<<dim3(32, 32), 256, 0, stream>>>(W1, W1t, 1024, 1024, 1024, 0);
  k_transconv<<<dim3(32, 384), 256, 0, stream>>>(W2, W2t, 1024, 12032, 12288, 1);

  k_gemm_relu<<<dim3(8, 128), 256, 0, stream>>>(x1b, W0t, b0, h1, 1024, 256);
  k_gemm_relu<<<dim3(8, 128), 256, 0, stream>>>(h1, W1t, b1, h2, 1024, 1024);
  k_gemm_spline<<<dim3(128, 128), 256, 0, stream>>>(h2, W2t, b2, x2, y2, ldp, 1024);
  k_reduce_ld<<<64, 256, 0, stream>>>(ldp, logdet);
}